// Round 1
// baseline (1559.755 us; speedup 1.0000x reference)
//
#include <hip/hip_runtime.h>

#define N_NODES 20000
#define N_EDGES 320000
#define HDIM    128
#define PI_F    3.14159265358979323846f
#define CUTOFF_R 5.0f

__device__ __forceinline__ float silu_f(float x) {
    return x / (1.0f + __expf(-x));
}

// ---------------------------------------------------------------------------
// LayerNorm: one wave per row (64 lanes x 2 elems), 4 rows per block
// ---------------------------------------------------------------------------
__global__ __launch_bounds__(256) void ln_kernel(
    const float* __restrict__ x, const float* __restrict__ gamma,
    const float* __restrict__ beta, float* __restrict__ out)
{
    int row  = blockIdx.x * 4 + (threadIdx.x >> 6);
    int lane = threadIdx.x & 63;
    if (row >= N_NODES) return;
    const float* xr = x + row * HDIM;
    float x0 = xr[lane], x1 = xr[lane + 64];
    float s  = x0 + x1;
    float s2 = x0 * x0 + x1 * x1;
#pragma unroll
    for (int m = 32; m >= 1; m >>= 1) {
        s  += __shfl_xor(s,  m, 64);
        s2 += __shfl_xor(s2, m, 64);
    }
    float mean = s * (1.0f / 128.0f);
    float var  = s2 * (1.0f / 128.0f) - mean * mean;
    float rstd = rsqrtf(var + 1e-5f);
    out[row * HDIM + lane]      = (x0 - mean) * rstd * gamma[lane]      + beta[lane];
    out[row * HDIM + lane + 64] = (x1 - mean) * rstd * gamma[lane + 64] + beta[lane + 64];
}

// ---------------------------------------------------------------------------
// Generic fp32 GEMM, K=128 fixed.  OUT[M x C] = act(A[M x 128] @ W[128 x C] + b)
// Block: 64 rows x 128 cols, 256 threads, each thread 4x8 outputs.
// ---------------------------------------------------------------------------
template <bool SILU, bool BIAS>
__global__ __launch_bounds__(256) void gemm_k128(
    const float* __restrict__ A, const float* __restrict__ W,
    const float* __restrict__ bias, float* __restrict__ out,
    int M, int C)
{
    __shared__ float As[64][33];   // [row][k] padded
    __shared__ float Ws[32][128];  // [k][col]

    int tid = threadIdx.x;
    int tx = tid & 15, ty = tid >> 4;
    int m0 = blockIdx.x * 64;
    int n0 = blockIdx.y * 128;

    float acc[4][8];
#pragma unroll
    for (int r = 0; r < 4; ++r)
#pragma unroll
        for (int c = 0; c < 8; ++c) acc[r][c] = 0.0f;

    for (int k0 = 0; k0 < 128; k0 += 32) {
        __syncthreads();
        // A tile 64x32 : 2 float4 per thread
#pragma unroll
        for (int p = 0; p < 2; ++p) {
            int f  = tid + p * 256;
            int ar = f >> 3, k4 = (f & 7) * 4;
            int gr = m0 + ar;
            float4 v = (gr < M) ? *(const float4*)&A[gr * 128 + k0 + k4]
                                : make_float4(0.f, 0.f, 0.f, 0.f);
            As[ar][k4 + 0] = v.x; As[ar][k4 + 1] = v.y;
            As[ar][k4 + 2] = v.z; As[ar][k4 + 3] = v.w;
        }
        // W tile 32x128 : 4 float4 per thread
#pragma unroll
        for (int p = 0; p < 4; ++p) {
            int f  = tid + p * 256;
            int kr = f >> 5, c4 = (f & 31) * 4;
            *(float4*)&Ws[kr][c4] = *(const float4*)&W[(k0 + kr) * C + n0 + c4];
        }
        __syncthreads();
#pragma unroll 8
        for (int k = 0; k < 32; ++k) {
            float av[4];
#pragma unroll
            for (int r = 0; r < 4; ++r) av[r] = As[ty * 4 + r][k];
            float4 w0 = *(float4*)&Ws[k][tx * 8];
            float4 w1 = *(float4*)&Ws[k][tx * 8 + 4];
            float wv[8] = {w0.x, w0.y, w0.z, w0.w, w1.x, w1.y, w1.z, w1.w};
#pragma unroll
            for (int r = 0; r < 4; ++r)
#pragma unroll
                for (int c = 0; c < 8; ++c) acc[r][c] += av[r] * wv[c];
        }
    }
#pragma unroll
    for (int r = 0; r < 4; ++r) {
        int gr = m0 + ty * 4 + r;
        if (gr < M) {
            float res[8];
#pragma unroll
            for (int c = 0; c < 8; ++c) {
                float v = acc[r][c];
                if (BIAS) v += bias[n0 + tx * 8 + c];
                if (SILU) v = silu_f(v);
                res[c] = v;
            }
            *(float4*)&out[gr * C + n0 + tx * 8]     = make_float4(res[0], res[1], res[2], res[3]);
            *(float4*)&out[gr * C + n0 + tx * 8 + 4] = make_float4(res[4], res[5], res[6], res[7]);
        }
    }
}

// ---------------------------------------------------------------------------
// Edge message: attn heads + msg (in-place over ef buffer) + scalar_agg atomics
// 2 edges per 256-thread block; 128 threads per edge; head = 16 lanes
// ---------------------------------------------------------------------------
__global__ __launch_bounds__(256) void edge_msg_kernel(
    float* __restrict__ efmsg, const float* __restrict__ ns,
    const int* __restrict__ eidx, const float* __restrict__ dist,
    const float* __restrict__ alpha, float* __restrict__ sagg)
{
    int e = blockIdx.x * 2 + (threadIdx.x >> 7);
    int h = threadIdx.x & 127;
    int i = eidx[e], j = eidx[N_EDGES + e];
    float ef  = efmsg[e * HDIM + h];
    float nsi = ns[i * HDIM + h];
    float nsj = ns[j * HDIM + h];
    float pre = silu_f(nsi + nsj + ef) * alpha[h];
#pragma unroll
    for (int m = 8; m >= 1; m >>= 1) pre += __shfl_xor(pre, m, 16);
    float d   = dist[e];
    float cut = (d < CUTOFF_R) ? 0.5f * (cosf(PI_F * d * (1.0f / CUTOFF_R)) + 1.0f) : 0.0f;
    float msg = nsj * ef * (pre * cut);
    efmsg[e * HDIM + h] = msg;
    atomicAdd(&sagg[i * HDIM + h], msg);
}

// ---------------------------------------------------------------------------
// W_p1 GEMM (E x 128 @ 128 x 256) + silu + vmsg scatter into vector_agg.
// Block: 32 rows x 256 cols (full width so s1/s2 stay in LDS).
// ---------------------------------------------------------------------------
__global__ __launch_bounds__(256) void gemm_p1_vmsg(
    const float* __restrict__ Amsg, const float* __restrict__ Wp1,
    const float* __restrict__ bp1, const float* __restrict__ node_vector,
    const int* __restrict__ eidx, const float* __restrict__ edge_vector,
    float* __restrict__ vagg)
{
    __shared__ float As[32][33];
    __shared__ float Ws[32][256];   // reused as S[32][256] after compute
    __shared__ int   ei_s[32], ej_s[32];
    __shared__ float ev_s[32][3];

    int tid = threadIdx.x;
    int tx = tid & 31, ty = tid >> 5;
    int e0 = blockIdx.x * 32;

    if (tid < 32) { ei_s[tid] = eidx[e0 + tid]; ej_s[tid] = eidx[N_EDGES + e0 + tid]; }
    if (tid >= 64 && tid < 160) {
        int t = tid - 64;
        ev_s[t / 3][t % 3] = edge_vector[e0 * 3 + t];
    }

    float acc[4][8];
#pragma unroll
    for (int r = 0; r < 4; ++r)
#pragma unroll
        for (int c = 0; c < 8; ++c) acc[r][c] = 0.0f;

    for (int k0 = 0; k0 < 128; k0 += 32) {
        __syncthreads();
        {   // A tile 32x32 : 1 float4 per thread
            int ar = tid >> 3, k4 = (tid & 7) * 4;
            float4 v = *(const float4*)&Amsg[(e0 + ar) * 128 + k0 + k4];
            As[ar][k4 + 0] = v.x; As[ar][k4 + 1] = v.y;
            As[ar][k4 + 2] = v.z; As[ar][k4 + 3] = v.w;
        }
#pragma unroll
        for (int p = 0; p < 8; ++p) {   // W tile 32x256 : 8 float4 per thread
            int f  = tid + p * 256;
            int kr = f >> 6, c4 = (f & 63) * 4;
            *(float4*)&Ws[kr][c4] = *(const float4*)&Wp1[(k0 + kr) * 256 + c4];
        }
        __syncthreads();
#pragma unroll 8
        for (int k = 0; k < 32; ++k) {
            float av[4];
#pragma unroll
            for (int r = 0; r < 4; ++r) av[r] = As[ty * 4 + r][k];
            float4 w0 = *(float4*)&Ws[k][tx * 8];
            float4 w1 = *(float4*)&Ws[k][tx * 8 + 4];
            float wv[8] = {w0.x, w0.y, w0.z, w0.w, w1.x, w1.y, w1.z, w1.w};
#pragma unroll
            for (int r = 0; r < 4; ++r)
#pragma unroll
                for (int c = 0; c < 8; ++c) acc[r][c] += av[r] * wv[c];
        }
    }
    __syncthreads();
    // store silu(acc + bias) into LDS (reuse Ws as S[32][256])
#pragma unroll
    for (int r = 0; r < 4; ++r)
#pragma unroll
        for (int c = 0; c < 8; ++c)
            Ws[ty * 4 + r][tx * 8 + c] = silu_f(acc[r][c] + bp1[tx * 8 + c]);
    __syncthreads();

    // epilogue: vmsg = node_vector[j]*s1 + s2*ev ; atomic into vector_agg[i]
#pragma unroll
    for (int p = 0; p < 16; ++p) {
        int idx = tid + p * 256;            // 0..4095
        int r = idx >> 7, h = idx & 127;
        float s1 = Ws[r][h], s2 = Ws[r][h + 128];
        int i = ei_s[r], j = ej_s[r];
#pragma unroll
        for (int d = 0; d < 3; ++d) {
            float v = node_vector[(j * 3 + d) * 128 + h] * s1 + s2 * ev_s[r][d];
            atomicAdd(&vagg[(i * 3 + d) * 128 + h], v);
        }
    }
}

// ---------------------------------------------------------------------------
// W_f GEMM (E x 128 @ 128 x 128) + silu + cross-product sum_phi + residual
// ---------------------------------------------------------------------------
__global__ __launch_bounds__(256) void gemm_wf_edgeout(
    const float* __restrict__ edge_feats, const float* __restrict__ Wf,
    const float* __restrict__ bf, const float* __restrict__ nvg,
    const int* __restrict__ eidx, const float* __restrict__ edge_vector,
    float* __restrict__ edge_out)
{
    __shared__ float As[64][33];
    __shared__ float Ws[32][128];
    __shared__ int   ei_s[64], ej_s[64];
    __shared__ float ev_s[64][3];

    int tid = threadIdx.x;
    int tx = tid & 15, ty = tid >> 4;
    int e0 = blockIdx.x * 64;

    if (tid < 64) { ei_s[tid] = eidx[e0 + tid]; ej_s[tid] = eidx[N_EDGES + e0 + tid]; }
    if (tid >= 64 && tid < 256) {
        int t = tid - 64;
        if (t < 192) ev_s[t / 3][t % 3] = edge_vector[e0 * 3 + t];
    }

    float acc[4][8];
#pragma unroll
    for (int r = 0; r < 4; ++r)
#pragma unroll
        for (int c = 0; c < 8; ++c) acc[r][c] = 0.0f;

    for (int k0 = 0; k0 < 128; k0 += 32) {
        __syncthreads();
#pragma unroll
        for (int p = 0; p < 2; ++p) {
            int f  = tid + p * 256;
            int ar = f >> 3, k4 = (f & 7) * 4;
            float4 v = *(const float4*)&edge_feats[(e0 + ar) * 128 + k0 + k4];
            As[ar][k4 + 0] = v.x; As[ar][k4 + 1] = v.y;
            As[ar][k4 + 2] = v.z; As[ar][k4 + 3] = v.w;
        }
#pragma unroll
        for (int p = 0; p < 4; ++p) {
            int f  = tid + p * 256;
            int kr = f >> 5, c4 = (f & 31) * 4;
            *(float4*)&Ws[kr][c4] = *(const float4*)&Wf[(k0 + kr) * 128 + c4];
        }
        __syncthreads();
#pragma unroll 8
        for (int k = 0; k < 32; ++k) {
            float av[4];
#pragma unroll
            for (int r = 0; r < 4; ++r) av[r] = As[ty * 4 + r][k];
            float4 w0 = *(float4*)&Ws[k][tx * 8];
            float4 w1 = *(float4*)&Ws[k][tx * 8 + 4];
            float wv[8] = {w0.x, w0.y, w0.z, w0.w, w1.x, w1.y, w1.z, w1.w};
#pragma unroll
            for (int r = 0; r < 4; ++r)
#pragma unroll
                for (int c = 0; c < 8; ++c) acc[r][c] += av[r] * wv[c];
        }
    }

#pragma unroll
    for (int r = 0; r < 4; ++r) {
        int row = ty * 4 + r;
        int e   = e0 + row;
        int i = ei_s[row], j = ej_s[row];
        float ev0 = ev_s[row][0], ev1 = ev_s[row][1], ev2 = ev_s[row][2];
        float nvi[3][8], nvj[3][8];
#pragma unroll
        for (int d = 0; d < 3; ++d) {
            float4 a0 = *(const float4*)&nvg[(i * 3 + d) * 128 + tx * 8];
            float4 a1 = *(const float4*)&nvg[(i * 3 + d) * 128 + tx * 8 + 4];
            nvi[d][0] = a0.x; nvi[d][1] = a0.y; nvi[d][2] = a0.z; nvi[d][3] = a0.w;
            nvi[d][4] = a1.x; nvi[d][5] = a1.y; nvi[d][6] = a1.z; nvi[d][7] = a1.w;
            float4 b0 = *(const float4*)&nvg[(j * 3 + d) * 128 + tx * 8];
            float4 b1 = *(const float4*)&nvg[(j * 3 + d) * 128 + tx * 8 + 4];
            nvj[d][0] = b0.x; nvj[d][1] = b0.y; nvj[d][2] = b0.z; nvj[d][3] = b0.w;
            nvj[d][4] = b1.x; nvj[d][5] = b1.y; nvj[d][6] = b1.z; nvj[d][7] = b1.w;
        }
        float4 f0 = *(const float4*)&edge_feats[e * 128 + tx * 8];
        float4 f1 = *(const float4*)&edge_feats[e * 128 + tx * 8 + 4];
        float efres[8] = {f0.x, f0.y, f0.z, f0.w, f1.x, f1.y, f1.z, f1.w};
        float res[8];
#pragma unroll
        for (int c = 0; c < 8; ++c) {
            float ci0 = nvi[1][c] * ev2 - nvi[2][c] * ev1;
            float ci1 = nvi[2][c] * ev0 - nvi[0][c] * ev2;
            float ci2 = nvi[0][c] * ev1 - nvi[1][c] * ev0;
            float cj0 = nvj[1][c] * ev2 - nvj[2][c] * ev1;
            float cj1 = nvj[2][c] * ev0 - nvj[0][c] * ev2;
            float cj2 = nvj[0][c] * ev1 - nvj[1][c] * ev0;
            float sp  = ci0 * cj0 + ci1 * cj1 + ci2 * cj2;
            float t   = silu_f(acc[r][c] + bf[tx * 8 + c]);
            res[c] = efres[c] + t * sp;
        }
        *(float4*)&edge_out[e * 128 + tx * 8]     = make_float4(res[0], res[1], res[2], res[3]);
        *(float4*)&edge_out[e * 128 + tx * 8 + 4] = make_float4(res[4], res[5], res[6], res[7]);
    }
}

// ---------------------------------------------------------------------------
// node_scalar += scalar_agg ; node_vector += vector_agg  (float4 elementwise)
// ---------------------------------------------------------------------------
__global__ __launch_bounds__(256) void node_add_kernel(
    const float* __restrict__ ns0, const float* __restrict__ sagg,
    const float* __restrict__ nv0, const float* __restrict__ vagg,
    float* __restrict__ ns_new, float* __restrict__ nv_new)
{
    int idx = blockIdx.x * 256 + threadIdx.x;   // float4 index
    const int nsf4 = N_NODES * HDIM / 4;        // 640000
    if (idx < nsf4) {
        float4 a = ((const float4*)ns0)[idx];
        float4 b = ((const float4*)sagg)[idx];
        ((float4*)ns_new)[idx] = make_float4(a.x + b.x, a.y + b.y, a.z + b.z, a.w + b.w);
    } else {
        int k = idx - nsf4;                     // < 1,920,000
        float4 a = ((const float4*)nv0)[k];
        float4 b = ((const float4*)vagg)[k];
        ((float4*)nv_new)[k] = make_float4(a.x + b.x, a.y + b.y, a.z + b.z, a.w + b.w);
    }
}

// ---------------------------------------------------------------------------
// Final node update: vec_tri / vec_qua / delta_scalar / delta_vector
// ---------------------------------------------------------------------------
__global__ __launch_bounds__(256) void final_node_kernel(
    const float* __restrict__ v12, const float* __restrict__ p123,
    const float* __restrict__ ns_new, const float* __restrict__ nv_new,
    float* __restrict__ out_s, float* __restrict__ out_v)
{
    int idx = blockIdx.x * 256 + threadIdx.x;   // n*128 + h
    int n = idx >> 7, h = idx & 127;
    float tri = 0.f, q2 = 0.f;
    float v1d[3];
#pragma unroll
    for (int d = 0; d < 3; ++d) {
        float v1 = v12[(n * 3 + d) * 256 + h];
        float v2 = v12[(n * 3 + d) * 256 + 128 + h];
        v1d[d] = v1;
        tri += v1 * v2;
        q2  += v2 * v2;
    }
    float nrm = sqrtf(q2 + 1e-8f);
    float qua = nrm * nrm * nrm;
    float p1 = p123[n * 384 + h];
    float p2 = p123[n * 384 + 128 + h];
    float p3 = p123[n * 384 + 256 + h];
    out_s[idx] = ns_new[idx] + (qua + tri) * p1 + p2;
#pragma unroll
    for (int d = 0; d < 3; ++d)
        out_v[(n * 3 + d) * 128 + h] = nv_new[(n * 3 + d) * 128 + h] + v1d[d] * p3;
}

// ---------------------------------------------------------------------------
extern "C" void kernel_launch(void* const* d_in, const int* in_sizes, int n_in,
                              void* d_out, int out_size, void* d_ws, size_t ws_size,
                              hipStream_t stream)
{
    const float* node_scalar = (const float*)d_in[0];
    const float* node_vector = (const float*)d_in[1];
    const int*   edge_index  = (const int*)d_in[2];
    const float* dist        = (const float*)d_in[3];
    const float* edge_feats  = (const float*)d_in[4];
    const float* edge_vector = (const float*)d_in[5];
    const float* ln_gamma    = (const float*)d_in[6];
    const float* ln_beta     = (const float*)d_in[7];
    const float* alpha       = (const float*)d_in[8];
    const float* W_cross     = (const float*)d_in[9];
    const float* W_node      = (const float*)d_in[10];
    const float* b_node      = (const float*)d_in[11];
    const float* W_edge      = (const float*)d_in[12];
    const float* b_edge      = (const float*)d_in[13];
    const float* W_p1        = (const float*)d_in[14];
    const float* b_p1        = (const float*)d_in[15];
    const float* W_p2        = (const float*)d_in[16];
    const float* b_p2        = (const float*)d_in[17];
    const float* W_vec       = (const float*)d_in[18];
    const float* W_f         = (const float*)d_in[19];
    const float* b_f         = (const float*)d_in[20];

    float* out_scalar = (float*)d_out;
    float* out_vector = out_scalar + N_NODES * HDIM;           // 2,560,000
    float* out_edge   = out_vector + N_NODES * 3 * HDIM;       // +7,680,000

    // workspace layout (floats), 64M floats = 256 MB total, aliased by phase
    float* ws         = (float*)d_ws;
    float* scalar_out = ws;                    // N*H   (later: ns_new)
    float* ns         = scalar_out + 2560000;  // N*H
    float* nv         = ns + 2560000;          // 3N*H  (later: nv_new)
    float* sagg       = nv + 7680000;          // N*H
    float* vagg       = sagg + 2560000;        // 3N*H
    float* efmsg      = vagg + 7680000;        // E*H   (later: v12, p123)
    float* v12        = efmsg;                 // 3N*256 = 15,360,000
    float* p123       = efmsg + 15360000;      // N*384  =  7,680,000

    // zero the two aggregation buffers (contiguous)
    hipMemsetAsync(sagg, 0, (size_t)(2560000 + 7680000) * sizeof(float), stream);

    // Phase A: node-level precompute
    hipLaunchKernelGGL(ln_kernel, dim3(5000), dim3(256), 0, stream,
                       node_scalar, ln_gamma, ln_beta, scalar_out);
    hipLaunchKernelGGL((gemm_k128<false, true>), dim3(313, 1), dim3(256), 0, stream,
                       scalar_out, W_node, b_node, ns, N_NODES, 128);
    hipLaunchKernelGGL((gemm_k128<false, false>), dim3(938, 1), dim3(256), 0, stream,
                       node_vector, W_cross, nullptr, nv, 3 * N_NODES, 128);

    // Phase B: edge pipeline
    hipLaunchKernelGGL((gemm_k128<true, true>), dim3(5000, 1), dim3(256), 0, stream,
                       edge_feats, W_edge, b_edge, efmsg, N_EDGES, 128);
    hipLaunchKernelGGL(edge_msg_kernel, dim3(160000), dim3(256), 0, stream,
                       efmsg, ns, edge_index, dist, alpha, sagg);
    hipLaunchKernelGGL(gemm_p1_vmsg, dim3(10000), dim3(256), 0, stream,
                       efmsg, W_p1, b_p1, node_vector, edge_index, edge_vector, vagg);
    hipLaunchKernelGGL(gemm_wf_edgeout, dim3(5000), dim3(256), 0, stream,
                       edge_feats, W_f, b_f, nv, edge_index, edge_vector, out_edge);

    // Phase C: node update
    hipLaunchKernelGGL(node_add_kernel, dim3(10000), dim3(256), 0, stream,
                       node_scalar, sagg, node_vector, vagg, scalar_out, nv);
    hipLaunchKernelGGL((gemm_k128<false, false>), dim3(938, 2), dim3(256), 0, stream,
                       nv, W_vec, nullptr, v12, 3 * N_NODES, 256);
    hipLaunchKernelGGL((gemm_k128<false, true>), dim3(313, 3), dim3(256), 0, stream,
                       scalar_out, W_p2, b_p2, p123, N_NODES, 384);
    hipLaunchKernelGGL(final_node_kernel, dim3(10000), dim3(256), 0, stream,
                       v12, p123, scalar_out, nv, out_scalar, out_vector);
}